// Round 3
// baseline (169.286 us; speedup 1.0000x reference)
//
#include <hip/hip_runtime.h>

// B=2, D=64, N=512, H=256, OUT=64
// mid[b] = sum_{c,i} relu( relu(hi[b,i]+hc[b,c]+b1) @ w2 + b2 ) @ w3 + N^2*b3
// out = relu(mid @ w4 + b4) @ w5 + b5

using f32x16  = __attribute__((ext_vector_type(16))) float;
using short8  = __attribute__((ext_vector_type(8))) short;
using float4v = __attribute__((ext_vector_type(4))) float;

__device__ __forceinline__ short f2bf(float f) {
    unsigned u = __float_as_uint(f);
    unsigned r = u + 0x7FFFu + ((u >> 16) & 1u);   // RNE
    return (short)(r >> 16);
}

// ---- prep (merged): blocks [0,1024): hi/hcb; blocks [1024,1280): w2t transpose
__global__ __launch_bounds__(256) void prep(const float* __restrict__ in,
                                            const float* __restrict__ w1,
                                            const float* __restrict__ b1,
                                            const float* __restrict__ w2,
                                            float* __restrict__ hi,
                                            float* __restrict__ hcb,
                                            short* __restrict__ w2t) {
    int tid = threadIdx.x;
    int bidx = blockIdx.x;
    if (bidx < 1024) {
        int b = bidx >> 9, n = bidx & 511;
        __shared__ float xs[64];
        if (tid < 64) xs[tid] = in[(size_t)(b * 64 + tid) * 512 + n];
        __syncthreads();
        float a0 = 0.f, a1 = 0.f;
#pragma unroll 8
        for (int d = 0; d < 64; ++d) {
            float xv = xs[d];
            a0 += xv * w1[d * 256 + tid];
            a1 += xv * w1[(64 + d) * 256 + tid];
        }
        size_t o = (size_t)(b * 512 + n) * 256 + tid;
        hi[o]  = a0;
        hcb[o] = a1 + b1[tid];
    } else {
        int idx = (bidx - 1024) * 256 + tid;
        int n = idx & 255, k = idx >> 8;
        w2t[n * 256 + k] = f2bf(w2[k * 256 + n]);
    }
}

// ---- big (v3): 512 persistent blocks, 16 tiles each; gen interleaved into the kk loop.
__global__ __launch_bounds__(256, 2) void big(const float* __restrict__ hi,
                                              const float* __restrict__ hcb,
                                              const short* __restrict__ w2t,
                                              const float* __restrict__ b2,
                                              float* __restrict__ partials) {
    __shared__ __align__(16) unsigned char tAraw[2][32768];   // 2 x 64 rows x 512 B

    const int tid = threadIdx.x;
    const int bid = blockIdx.x;                 // [0,512)
    const int b   = bid >> 8, rem = bid & 255;
    const int cc  = rem >> 2, icg = rem & 3;

    const float* __restrict__ hib  = hi  + (size_t)b * (512 * 256);
    const float* __restrict__ hcbb = hcb + (size_t)b * (512 * 256);

    const int q    = tid >> 6;      // wave id: gen row-quarter AND mfma col-group
    const int c64  = tid & 63;      // gen: 4-float column group
    const int lane = tid & 63;
    const int h = lane >> 5, l31 = lane & 31, l7 = lane & 7;
    const int colbase = q * 64;

    // gen constants
    const int wgran = c64 >> 1;
    const int wsub  = (c64 & 1) * 8;

    // context rows (2 per thread, float4 of its col group)
    float4v cv4[2];
    cv4[0] = *reinterpret_cast<const float4v*>(&hcbb[(size_t)(cc * 8 + 2 * q) * 256 + 4 * c64]);
    cv4[1] = *reinterpret_cast<const float4v*>(&hcbb[(size_t)(cc * 8 + 2 * q + 1) * 256 + 4 * c64]);

    // persistent B fragments: 64 cols x K=256 per wave
    short8 bfr[2][16];
    const short8* w2v = reinterpret_cast<const short8*>(w2t);
#pragma unroll
    for (int cf = 0; cf < 2; ++cf)
#pragma unroll
        for (int kk = 0; kk < 16; ++kk)
            bfr[cf][kk] = w2v[(size_t)(colbase + cf * 32 + l31) * 32 + kk * 2 + h];

    const float b2v0 = b2[colbase + l31];
    const float b2v1 = b2[colbase + 32 + l31];
    float psum0 = 0.f, psum1 = 0.f;

    auto genpair = [&](unsigned char* wb, float4v hv, int p) {
        float4v v0 = hv + cv4[0];
        float4v v1 = hv + cv4[1];
#pragma unroll
        for (int e = 0; e < 4; ++e) {
            v0[e] = fmaxf(v0[e], 0.f);
            v1[e] = fmaxf(v1[e], 0.f);
        }
        unsigned lo0, hi0, lo1, hi1;
        float a, bb;
        a = v0[0]; bb = v0[1];
        asm("v_cvt_pk_bf16_f32 %0, %1, %2" : "=v"(lo0) : "v"(a), "v"(bb));
        a = v0[2]; bb = v0[3];
        asm("v_cvt_pk_bf16_f32 %0, %1, %2" : "=v"(hi0) : "v"(a), "v"(bb));
        a = v1[0]; bb = v1[1];
        asm("v_cvt_pk_bf16_f32 %0, %1, %2" : "=v"(lo1) : "v"(a), "v"(bb));
        a = v1[2]; bb = v1[3];
        asm("v_cvt_pk_bf16_f32 %0, %1, %2" : "=v"(hi1) : "v"(a), "v"(bb));
        const int goff = ((wgran ^ p) << 4) + wsub;
        const int r0 = q * 16 + p;
        uint2 w0; w0.x = lo0; w0.y = hi0;
        uint2 w1v; w1v.x = lo1; w1v.y = hi1;
        *reinterpret_cast<uint2*>(wb + r0 * 512 + goff) = w0;          // row r0   (cv4[0])
        *reinterpret_cast<uint2*>(wb + (r0 + 8) * 512 + goff) = w1v;   // row r0+8 (cv4[1])
    };

    // ---- prologue: generate tile 0 into tAraw[0]
    {
        const float* hsrc = hib + (size_t)(icg * 16 * 8) * 256 + 4 * c64;
#pragma unroll
        for (int p = 0; p < 8; ++p) {
            float4v hv = *reinterpret_cast<const float4v*>(hsrc + p * 256);
            genpair(tAraw[0], hv, p);
        }
    }
    __syncthreads();

    const unsigned char* rb = tAraw[0];
    unsigned char* wb = tAraw[1];
    const float* hsrc = hib + (size_t)((icg * 16 + 1) * 8) * 256 + 4 * c64;

    const int rbase0 = l31 * 512;
    const int rbase1 = (32 + l31) * 512;

    for (int t = 0; t < 15; ++t) {
        f32x16 acc00, acc01, acc10, acc11;
#pragma unroll
        for (int e = 0; e < 16; ++e) {
            acc00[e] = b2v0; acc01[e] = b2v1;
            acc10[e] = b2v0; acc11[e] = b2v1;
        }
        float4v hv4[8];
#pragma unroll
        for (int kk = 0; kk < 16; ++kk) {
            if (kk < 8) hv4[kk] = *reinterpret_cast<const float4v*>(hsrc + kk * 256);
            const int sc = ((2 * kk + h) ^ l7) << 4;
            short8 a0 = *reinterpret_cast<const short8*>(rb + rbase0 + sc);
            short8 a1 = *reinterpret_cast<const short8*>(rb + rbase1 + sc);
            __builtin_amdgcn_s_setprio(1);
            acc00 = __builtin_amdgcn_mfma_f32_32x32x16_bf16(a0, bfr[0][kk], acc00, 0, 0, 0);
            acc01 = __builtin_amdgcn_mfma_f32_32x32x16_bf16(a0, bfr[1][kk], acc01, 0, 0, 0);
            acc10 = __builtin_amdgcn_mfma_f32_32x32x16_bf16(a1, bfr[0][kk], acc10, 0, 0, 0);
            acc11 = __builtin_amdgcn_mfma_f32_32x32x16_bf16(a1, bfr[1][kk], acc11, 0, 0, 0);
            __builtin_amdgcn_s_setprio(0);
            if (kk >= 4 && kk < 12) genpair(wb, hv4[kk - 4], kk - 4);
        }
        float s0 = 0.f, s1 = 0.f;
#pragma unroll
        for (int e = 0; e < 16; ++e) {
            s0 += fmaxf(acc00[e], 0.f);
            s0 += fmaxf(acc10[e], 0.f);
            s1 += fmaxf(acc01[e], 0.f);
            s1 += fmaxf(acc11[e], 0.f);
        }
        psum0 += s0;
        psum1 += s1;
        __syncthreads();
        const unsigned char* tmp = rb; rb = wb; wb = const_cast<unsigned char*>(tmp);
        hsrc += 8 * 256;
    }

    // ---- tail tile (t=15): MFMA only
    {
        f32x16 acc00, acc01, acc10, acc11;
#pragma unroll
        for (int e = 0; e < 16; ++e) {
            acc00[e] = b2v0; acc01[e] = b2v1;
            acc10[e] = b2v0; acc11[e] = b2v1;
        }
#pragma unroll
        for (int kk = 0; kk < 16; ++kk) {
            const int sc = ((2 * kk + h) ^ l7) << 4;
            short8 a0 = *reinterpret_cast<const short8*>(rb + rbase0 + sc);
            short8 a1 = *reinterpret_cast<const short8*>(rb + rbase1 + sc);
            __builtin_amdgcn_s_setprio(1);
            acc00 = __builtin_amdgcn_mfma_f32_32x32x16_bf16(a0, bfr[0][kk], acc00, 0, 0, 0);
            acc01 = __builtin_amdgcn_mfma_f32_32x32x16_bf16(a0, bfr[1][kk], acc01, 0, 0, 0);
            acc10 = __builtin_amdgcn_mfma_f32_32x32x16_bf16(a1, bfr[0][kk], acc10, 0, 0, 0);
            acc11 = __builtin_amdgcn_mfma_f32_32x32x16_bf16(a1, bfr[1][kk], acc11, 0, 0, 0);
            __builtin_amdgcn_s_setprio(0);
        }
        float s0 = 0.f, s1 = 0.f;
#pragma unroll
        for (int e = 0; e < 16; ++e) {
            s0 += fmaxf(acc00[e], 0.f);
            s0 += fmaxf(acc10[e], 0.f);
            s1 += fmaxf(acc01[e], 0.f);
            s1 += fmaxf(acc11[e], 0.f);
        }
        psum0 += s0;
        psum1 += s1;
    }

    psum0 += __shfl_xor(psum0, 32);
    psum1 += __shfl_xor(psum1, 32);
    if (h == 0) {
        partials[(size_t)bid * 256 + colbase + l31]      = psum0;
        partials[(size_t)bid * 256 + colbase + 32 + l31] = psum1;
    }
}

// ---- final tail: sum 256 partial rows per batch, then tiny MLP chain
__global__ __launch_bounds__(256) void finalK(const float* __restrict__ partials,
                                              const float* __restrict__ w3,
                                              const float* __restrict__ b3,
                                              const float* __restrict__ w4,
                                              const float* __restrict__ b4,
                                              const float* __restrict__ w5,
                                              const float* __restrict__ b5,
                                              float* __restrict__ out) {
    __shared__ float su[256], mid[256], o[256];
    int tid = threadIdx.x;
    for (int b = 0; b < 2; ++b) {
        const float* pb = partials + (size_t)b * 256 * 256;
        float s = 0.f;
#pragma unroll 8
        for (int r = 0; r < 256; ++r) s += pb[(size_t)r * 256 + tid];
        su[tid] = s;
        __syncthreads();
        float m = 262144.0f * b3[tid];
        for (int k = 0; k < 256; ++k) m += su[k] * w3[k * 256 + tid];
        mid[tid] = m;
        __syncthreads();
        float ov = b4[tid];
        for (int k = 0; k < 256; ++k) ov += mid[k] * w4[k * 256 + tid];
        o[tid] = fmaxf(ov, 0.f);
        __syncthreads();
        if (tid < 64) {
            float r = b5[tid];
            for (int k = 0; k < 256; ++k) r += o[k] * w5[k * 64 + tid];
            out[b * 64 + tid] = r;
        }
        __syncthreads();
    }
}

extern "C" void kernel_launch(void* const* d_in, const int* in_sizes, int n_in,
                              void* d_out, int out_size, void* d_ws, size_t ws_size,
                              hipStream_t stream) {
    const float* in = (const float*)d_in[0];
    const float* w1 = (const float*)d_in[1];
    const float* b1 = (const float*)d_in[2];
    const float* w2 = (const float*)d_in[3];
    const float* b2 = (const float*)d_in[4];
    const float* w3 = (const float*)d_in[5];
    const float* b3 = (const float*)d_in[6];
    const float* w4 = (const float*)d_in[7];
    const float* b4 = (const float*)d_in[8];
    const float* w5 = (const float*)d_in[9];
    const float* b5 = (const float*)d_in[10];
    float* out = (float*)d_out;

    char* ws = (char*)d_ws;
    float* hi       = (float*)(ws);                                   // 1 MB
    float* hcb      = (float*)(ws + (1u << 20));                      // 1 MB
    short* w2t      = (short*)(ws + (2u << 20));                      // 128 KB
    float* partials = (float*)(ws + (2u << 20) + (1u << 18));         // 512 KB

    prep<<<1280, 256, 0, stream>>>(in, w1, b1, w2, hi, hcb, w2t);
    big<<<512, 256, 0, stream>>>(hi, hcb, w2t, b2, partials);
    finalK<<<1, 256, 0, stream>>>(partials, w3, b3, w4, b4, w5, b5, out);
}

// Round 4
// 133.035 us; speedup vs baseline: 1.2725x; 1.2725x over previous
//
#include <hip/hip_runtime.h>

// B=2, D=64, N=512, H=256, OUT=64
// mid[b] = sum_{c,i} relu( relu(hi[b,i]+hc[b,c]+b1) @ w2 + b2 ) @ w3 + N^2*b3
// out = relu(mid @ w4 + b4) @ w5 + b5

using f32x16  = __attribute__((ext_vector_type(16))) float;
using short8  = __attribute__((ext_vector_type(8))) short;
using float2v = __attribute__((ext_vector_type(2))) float;

__device__ __forceinline__ short f2bf(float f) {
    unsigned u = __float_as_uint(f);
    unsigned r = u + 0x7FFFu + ((u >> 16) & 1u);   // RNE
    return (short)(r >> 16);
}

// ---- prep (merged): blocks [0,1024): hi/hcb; blocks [1024,1280): w2t transpose
__global__ __launch_bounds__(256) void prep(const float* __restrict__ in,
                                            const float* __restrict__ w1,
                                            const float* __restrict__ b1,
                                            const float* __restrict__ w2,
                                            float* __restrict__ hi,
                                            float* __restrict__ hcb,
                                            short* __restrict__ w2t) {
    int tid = threadIdx.x;
    int bidx = blockIdx.x;
    if (bidx < 1024) {
        int b = bidx >> 9, n = bidx & 511;
        __shared__ float xs[64];
        if (tid < 64) xs[tid] = in[(size_t)(b * 64 + tid) * 512 + n];
        __syncthreads();
        float a0 = 0.f, a1 = 0.f;
#pragma unroll 8
        for (int d = 0; d < 64; ++d) {
            float xv = xs[d];
            a0 += xv * w1[d * 256 + tid];
            a1 += xv * w1[(64 + d) * 256 + tid];
        }
        size_t o = (size_t)(b * 512 + n) * 256 + tid;
        hi[o]  = a0;
        hcb[o] = a1 + b1[tid];
    } else {
        int idx = (bidx - 1024) * 256 + tid;
        int n = idx & 255, k = idx >> 8;
        w2t[n * 256 + k] = f2bf(w2[k * 256 + n]);
    }
}

// ---- big (v4): R1 structure + load-early/gen-late split + b2-fold + setprio.
__global__ __launch_bounds__(256, 2) void big(const float* __restrict__ hi,
                                              const float* __restrict__ hcb,
                                              const short* __restrict__ w2t,
                                              const float* __restrict__ b2,
                                              float* __restrict__ partials) {
    __shared__ __align__(16) unsigned tA[2][64 * 128];   // 2 x 32 KB

    const int tid = threadIdx.x;
    const int bid = blockIdx.x;                 // [0,512)
    const int b   = bid >> 8, rem = bid & 255;
    const int cc  = rem >> 2, icg = rem & 3;

    const float* __restrict__ hib  = hi  + (size_t)b * (512 * 256);
    const float* __restrict__ hcbb = hcb + (size_t)b * (512 * 256);

    const int cp   = tid & 127, half = tid >> 7;   // A-gen mapping
    const int lane = tid & 63;                      // MFMA mapping
    const int wid  = tid >> 6;
    const int h = lane >> 5, l31 = lane & 31, l7 = lane & 7;
    const int colbase = wid * 64;

    // context rows (fixed for the whole block)
    float2v cv2[4];
#pragma unroll
    for (int j = 0; j < 4; ++j)
        cv2[j] = *reinterpret_cast<const float2v*>(
            &hcbb[(size_t)(cc * 8 + half * 4 + j) * 256 + 2 * cp]);

    // persistent B fragments: 64 cols x K=256 bf16 per wave = 128 VGPRs
    short8 bfr[2][16];
    const short8* w2v = reinterpret_cast<const short8*>(w2t);
#pragma unroll
    for (int cf = 0; cf < 2; ++cf)
#pragma unroll
        for (int kk = 0; kk < 16; ++kk)
            bfr[cf][kk] = w2v[(size_t)(colbase + cf * 32 + l31) * 32 + kk * 2 + h];

    const float b2v0 = b2[colbase + l31];
    const float b2v1 = b2[colbase + 32 + l31];
    float psum0 = 0.f, psum1 = 0.f;

    const int cbase = cp >> 2, woff = cp & 3;

    auto loadhv = [&](int ic, float2v* hv2) {
#pragma unroll
        for (int j = 0; j < 8; ++j)
            hv2[j] = *reinterpret_cast<const float2v*>(
                &hib[(size_t)(ic * 8 + j) * 256 + 2 * cp]);
    };
    auto genw = [&](const float2v* hv2, unsigned* __restrict__ buf) {
#pragma unroll
        for (int p = 0; p < 32; ++p) {
            float ax = hv2[p & 7][0] + cv2[p >> 3][0];
            float ay = hv2[p & 7][1] + cv2[p >> 3][1];
            ax = fmaxf(ax, 0.f);
            ay = fmaxf(ay, 0.f);
            unsigned pk;
            asm("v_cvt_pk_bf16_f32 %0, %1, %2" : "=v"(pk) : "v"(ax), "v"(ay));
            // row = half*32+p; 16B-chunk XOR swizzle keyed on row&7 (= p&7)
            buf[(half * 32 + p) * 128 + (((cbase ^ (p & 7)) << 2) + woff)] = pk;
        }
    };

    // ---- prologue: generate tile 0
    {
        float2v hv2[8];
        loadhv(icg * 16, hv2);
        genw(hv2, tA[0]);
    }
    __syncthreads();

    for (int t = 0; t < 16; ++t) {
        const int cur = t & 1;

        // issue next tile's global loads early (hide L2 latency under MFMA)
        float2v hv2[8];
        if (t < 15) loadhv(icg * 16 + t + 1, hv2);

        const short8* tAv = reinterpret_cast<const short8*>(tA[cur]);
        f32x16 acc00, acc01, acc10, acc11;
#pragma unroll
        for (int e = 0; e < 16; ++e) {
            acc00[e] = b2v0; acc01[e] = b2v1;
            acc10[e] = b2v0; acc11[e] = b2v1;
        }
#pragma unroll
        for (int kk = 0; kk < 16; ++kk) {
            const int sc = (kk * 2 + h) ^ l7;          // swizzled 16B chunk
            short8 a0 = tAv[l31 * 32 + sc];
            short8 a1 = tAv[(32 + l31) * 32 + sc];
            __builtin_amdgcn_s_setprio(1);
            acc00 = __builtin_amdgcn_mfma_f32_32x32x16_bf16(a0, bfr[0][kk], acc00, 0, 0, 0);
            acc01 = __builtin_amdgcn_mfma_f32_32x32x16_bf16(a0, bfr[1][kk], acc01, 0, 0, 0);
            acc10 = __builtin_amdgcn_mfma_f32_32x32x16_bf16(a1, bfr[0][kk], acc10, 0, 0, 0);
            acc11 = __builtin_amdgcn_mfma_f32_32x32x16_bf16(a1, bfr[1][kk], acc11, 0, 0, 0);
            __builtin_amdgcn_s_setprio(0);
        }

        // gen-compute+write of tile t+1 (loads already arrived under MFMA)
        if (t < 15) genw(hv2, tA[cur ^ 1]);

        float s0 = 0.f, s1 = 0.f;
#pragma unroll
        for (int e = 0; e < 16; ++e) {
            s0 += fmaxf(acc00[e], 0.f);
            s0 += fmaxf(acc10[e], 0.f);
            s1 += fmaxf(acc01[e], 0.f);
            s1 += fmaxf(acc11[e], 0.f);
        }
        psum0 += s0;
        psum1 += s1;
        __syncthreads();
    }

    psum0 += __shfl_xor(psum0, 32);
    psum1 += __shfl_xor(psum1, 32);
    if (h == 0) {
        partials[(size_t)bid * 256 + colbase + l31]      = psum0;
        partials[(size_t)bid * 256 + colbase + 32 + l31] = psum1;
    }
}

// ---- final tail: both batches in parallel (512 threads)
__global__ __launch_bounds__(512) void finalK(const float* __restrict__ partials,
                                              const float* __restrict__ w3,
                                              const float* __restrict__ b3,
                                              const float* __restrict__ w4,
                                              const float* __restrict__ b4,
                                              const float* __restrict__ w5,
                                              const float* __restrict__ b5,
                                              float* __restrict__ out) {
    __shared__ float su[2][256], mid[2][256], o[2][256];
    int tid = threadIdx.x;
    int b = tid >> 8, col = tid & 255;
    const float* pb = partials + (size_t)b * 256 * 256;
    float s = 0.f;
#pragma unroll 8
    for (int r = 0; r < 256; ++r) s += pb[(size_t)r * 256 + col];
    su[b][col] = s;
    __syncthreads();
    float m = 262144.0f * b3[col];
    for (int k = 0; k < 256; ++k) m += su[b][k] * w3[k * 256 + col];
    mid[b][col] = m;
    __syncthreads();
    float ov = b4[col];
    for (int k = 0; k < 256; ++k) ov += mid[b][k] * w4[k * 256 + col];
    o[b][col] = fmaxf(ov, 0.f);
    __syncthreads();
    if (col < 64) {
        float r = b5[col];
        for (int k = 0; k < 256; ++k) r += o[b][k] * w5[k * 64 + col];
        out[b * 64 + col] = r;
    }
}

extern "C" void kernel_launch(void* const* d_in, const int* in_sizes, int n_in,
                              void* d_out, int out_size, void* d_ws, size_t ws_size,
                              hipStream_t stream) {
    const float* in = (const float*)d_in[0];
    const float* w1 = (const float*)d_in[1];
    const float* b1 = (const float*)d_in[2];
    const float* w2 = (const float*)d_in[3];
    const float* b2 = (const float*)d_in[4];
    const float* w3 = (const float*)d_in[5];
    const float* b3 = (const float*)d_in[6];
    const float* w4 = (const float*)d_in[7];
    const float* b4 = (const float*)d_in[8];
    const float* w5 = (const float*)d_in[9];
    const float* b5 = (const float*)d_in[10];
    float* out = (float*)d_out;

    char* ws = (char*)d_ws;
    float* hi       = (float*)(ws);                                   // 1 MB
    float* hcb      = (float*)(ws + (1u << 20));                      // 1 MB
    short* w2t      = (short*)(ws + (2u << 20));                      // 128 KB
    float* partials = (float*)(ws + (2u << 20) + (1u << 18));         // 512 KB

    prep<<<1280, 256, 0, stream>>>(in, w1, b1, w2, hi, hcb, w2t);
    big<<<512, 256, 0, stream>>>(hi, hcb, w2t, b2, partials);
    finalK<<<1, 512, 0, stream>>>(partials, w3, b3, w4, b4, w5, b5, out);
}